// Round 2
// baseline (3149.013 us; speedup 1.0000x reference)
//
#include <hip/hip_runtime.h>

// VectorQuantizer: x (64,32,32,128) f32, embeddings (128,1024) f32.
// out[row] = embeddings.T[argmin_k ||x_row - e_k||^2]
//
// Two-phase argmin for bit-robustness on near-ties:
//   phase 1 (fp32, fast): score = nrm[k] - 2*f.e_k; track best + 2nd best.
//     rows with (b2-b1) < MARGIN go on a worklist (expect ~100-200 rows).
//   phase 2 (fp64, exact): re-argmin worklist rows; matches f64 reference.
//
// ws layout: et (1024x128 f32) | nrm (1024 f32) | idx (65536 i32)
//            | wl_count (i32) | wl (65536 i32)

#define NROWS 65536
#define DDIM 128
#define KCODES 1024
#define KT 8
#define MARGIN 0.03125f

__global__ void k_transpose(const float* __restrict__ e, float* __restrict__ et) {
    int gid = blockIdx.x * blockDim.x + threadIdx.x;   // 0..131071
    int d = gid >> 10;
    int k = gid & 1023;
    et[k * DDIM + d] = e[gid];
}

__global__ void k_norms(const float* __restrict__ e, float* __restrict__ nrm) {
    int k = blockIdx.x * blockDim.x + threadIdx.x;     // 0..1023
    float s = 0.f;
    #pragma unroll 4
    for (int d = 0; d < DDIM; ++d) {
        float v = e[d * KCODES + k];
        s = fmaf(v, v, s);
    }
    nrm[k] = s;
}

// 256 threads = 128 rows x 2 k-halves. Grid = NROWS/128 = 512 blocks.
__global__ __launch_bounds__(256, 2) void k_argmin(const float* __restrict__ x,
                                                   const float* __restrict__ e,
                                                   const float* __restrict__ nrm,
                                                   int* __restrict__ idx,
                                                   int* __restrict__ wl_count,
                                                   int* __restrict__ wl) {
    __shared__ float s_b1[256];
    __shared__ float s_b2[256];
    __shared__ int   s_bi[256];

    const int tid = threadIdx.x;
    const int row_local = tid & 127;
    const int half = tid >> 7;                 // uniform within each wave64
    const int row = blockIdx.x * 128 + row_local;

    // Row into registers (32 x float4 = 128 VGPRs).
    float4 f[32];
    const float4* xr = reinterpret_cast<const float4*>(x + (size_t)row * DDIM);
    #pragma unroll
    for (int i = 0; i < 32; ++i) f[i] = xr[i];

    float b1 = 3.4e38f, b2 = 3.4e38f;
    int bidx = 0;
    // readfirstlane: tell the compiler kbeg is wave-uniform -> s_load for e/nrm
    const int kbeg = __builtin_amdgcn_readfirstlane(half) * (KCODES / 2);
    const int kend = kbeg + (KCODES / 2);

    for (int k0 = kbeg; k0 < kend; k0 += KT) {
        float acc[KT];
        #pragma unroll
        for (int j = 0; j < KT; ++j) acc[j] = 0.f;

        #pragma unroll
        for (int d4 = 0; d4 < 32; ++d4) {
            float4 fv = f[d4];
            #pragma unroll
            for (int j = 0; j < KT; ++j) {
                acc[j] = fmaf(fv.x, e[(4 * d4 + 0) * KCODES + k0 + j], acc[j]);
                acc[j] = fmaf(fv.y, e[(4 * d4 + 1) * KCODES + k0 + j], acc[j]);
                acc[j] = fmaf(fv.z, e[(4 * d4 + 2) * KCODES + k0 + j], acc[j]);
                acc[j] = fmaf(fv.w, e[(4 * d4 + 3) * KCODES + k0 + j], acc[j]);
            }
        }

        #pragma unroll
        for (int j = 0; j < KT; ++j) {
            float s = fmaf(-2.f, acc[j], nrm[k0 + j]);
            if (s < b1) { b2 = b1; b1 = s; bidx = k0 + j; }   // strict <: first-min
            else if (s < b2) { b2 = s; }
        }
    }

    s_b1[tid] = b1; s_b2[tid] = b2; s_bi[tid] = bidx;
    __syncthreads();
    if (half == 0) {
        float ob1 = s_b1[tid + 128], ob2 = s_b2[tid + 128];
        int   obi = s_bi[tid + 128];
        float nb1, nb2; int nbi;
        if (ob1 < b1) { nb1 = ob1; nbi = obi;  nb2 = fminf(b1, ob2); }
        else          { nb1 = b1;  nbi = bidx; nb2 = fminf(b2, ob1); }
        idx[row] = nbi;
        if (nb2 - nb1 < MARGIN) {
            int slot = atomicAdd(wl_count, 1);
            wl[slot] = row;
        }
    }
}

// Exact (f64) re-argmin for near-tie rows. Grid-stride over worklist.
__global__ __launch_bounds__(256) void k_fix(const float* __restrict__ x,
                                             const float* __restrict__ e,
                                             const int* __restrict__ wl_count,
                                             const int* __restrict__ wl,
                                             int* __restrict__ idx) {
    __shared__ float  fs[DDIM];
    __shared__ double sv[256];
    __shared__ int    si[256];
    const int tid = threadIdx.x;
    const int n = *wl_count;

    for (int i = blockIdx.x; i < n; i += gridDim.x) {
        const int row = wl[i];
        if (tid < DDIM) fs[tid] = x[(size_t)row * DDIM + tid];
        __syncthreads();

        double b = 1e300; int bi = 0;
        #pragma unroll
        for (int kk = 0; kk < 4; ++kk) {
            const int k = tid + kk * 256;          // lanes read consecutive k: coalesced
            double dot = 0.0, nr = 0.0;
            for (int d = 0; d < DDIM; ++d) {
                double ev = (double)e[d * KCODES + k];
                dot = fma((double)fs[d], ev, dot);
                nr  = fma(ev, ev, nr);
            }
            double sc = nr - 2.0 * dot;
            if (sc < b) { b = sc; bi = k; }        // ascending k: first-min
        }
        sv[tid] = b; si[tid] = bi;
        __syncthreads();
        for (int off = 128; off > 0; off >>= 1) {
            if (tid < off) {
                double ov = sv[tid + off]; int oi = si[tid + off];
                if (ov < sv[tid] || (ov == sv[tid] && oi < si[tid])) {
                    sv[tid] = ov; si[tid] = oi;
                }
            }
            __syncthreads();
        }
        if (tid == 0) idx[row] = si[0];
        __syncthreads();   // fs/sv reused next iteration
    }
}

// One float4 of output per thread. 32 lanes share a row -> coalesced et read.
__global__ void k_gather(const float* __restrict__ et, const int* __restrict__ idx,
                         float* __restrict__ out) {
    int gid = blockIdx.x * blockDim.x + threadIdx.x;   // 0 .. NROWS*32-1
    int row = gid >> 5;
    int d4 = gid & 31;
    const float4* src = reinterpret_cast<const float4*>(et + (size_t)idx[row] * DDIM);
    reinterpret_cast<float4*>(out)[gid] = src[d4];
}

extern "C" void kernel_launch(void* const* d_in, const int* in_sizes, int n_in,
                              void* d_out, int out_size, void* d_ws, size_t ws_size,
                              hipStream_t stream) {
    const float* x = (const float*)d_in[0];
    const float* e = (const float*)d_in[1];
    float* out = (float*)d_out;

    float* et       = (float*)d_ws;                      // 512 KB
    float* nrm      = et + (size_t)KCODES * DDIM;        // 4 KB
    int*   idx      = (int*)(nrm + KCODES);              // 256 KB
    int*   wl_count = idx + NROWS;                       // 4 B
    int*   wl       = wl_count + 1;                      // 256 KB

    hipMemsetAsync(wl_count, 0, sizeof(int), stream);

    k_transpose<<<(KCODES * DDIM) / 256, 256, 0, stream>>>(e, et);
    k_norms<<<KCODES / 256, 256, 0, stream>>>(e, nrm);
    k_argmin<<<NROWS / 128, 256, 0, stream>>>(x, e, nrm, idx, wl_count, wl);
    k_fix<<<128, 256, 0, stream>>>(x, e, wl_count, wl, idx);
    k_gather<<<(NROWS * (DDIM / 4)) / 256, 256, 0, stream>>>(et, idx, out);
}

// Round 3
// 246.122 us; speedup vs baseline: 12.7945x; 12.7945x over previous
//
#include <hip/hip_runtime.h>

// VectorQuantizer: x (64,32,32,128) f32, embeddings (128,1024) f32.
// out = x + (e.T[argmin_k ||x_row - e_k||^2] - x)   (f32 STE, matches ref)
//
// Cascade:
//   phase 1: bf16 MFMA (32x32x16) scores s = nrm[k] - 2*dot; per-row best+2nd.
//            gap < MARGIN1 (0.5 ~ 14 sigma of bf16 error) -> worklist 1.
//   phase 2: fp32 re-scan of wl1 rows (8 rows share one e sweep); gap < MARGIN2 -> wl2.
//   phase 3: f64 re-scan of wl2 rows (exact; validated last round).
// MFMA A/B packed with the SAME k-bijection -> dot invariant to k-permutation;
// C/D layout is the HW-verified col=lane&31, row=(reg&3)+8*(reg>>2)+4*(lane>>5).

#define NROWS 65536
#define DDIM 128
#define KCODES 1024
#define MARGIN1 0.5f
#define MARGIN2 2e-4

typedef __attribute__((ext_vector_type(8))) short short8;
typedef __attribute__((ext_vector_type(16))) float f32x16;

__device__ inline short f2bf(float f) {           // RNE f32 -> bf16 bits
    union { float f; unsigned u; } v; v.f = f;
    unsigned r = v.u + 0x7fffu + ((v.u >> 16) & 1u);
    return (short)(r >> 16);
}

// ---------- prep ----------
__global__ void k_transpose(const float* __restrict__ e, float* __restrict__ et) {
    int gid = blockIdx.x * blockDim.x + threadIdx.x;   // 131072
    int d = gid >> 10, k = gid & 1023;
    et[k * DDIM + d] = e[gid];
}

__global__ void k_norms(const float* __restrict__ e, float* __restrict__ nrm,
                        double* __restrict__ nrm64) {
    int k = blockIdx.x * blockDim.x + threadIdx.x;     // 1024
    double s = 0.0;
    for (int d = 0; d < DDIM; ++d) {
        double v = (double)e[d * KCODES + k];
        s = fma(v, v, s);
    }
    nrm64[k] = s; nrm[k] = (float)s;
}

// ep[(nt*8 + c)*64 + lane] = 8 bf16: e[k = c*16 + (lane>>5)*8 + j][col = nt*32 + (lane&31)]
__global__ void k_pack_e(const float* __restrict__ e, ushort* __restrict__ ep) {
    int t = blockIdx.x * blockDim.x + threadIdx.x;     // 16384
    int lane = t & 63, c = (t >> 6) & 7, nt = t >> 9;
    int col = nt * 32 + (lane & 31);
    int kbase = c * 16 + ((lane >> 5) << 3);
    union { ushort u[8]; uint4 q; } pk;
    #pragma unroll
    for (int j = 0; j < 8; ++j)
        pk.u[j] = (ushort)f2bf(e[(kbase + j) * KCODES + col]);
    reinterpret_cast<uint4*>(ep)[t] = pk.q;
}

// ---------- phase 1: MFMA argmin ----------
// grid 1024 x 256. Block = 2 rowtiles(32 rows) x 2 N-halves. 4 waves.
__global__ __launch_bounds__(256, 4) void k_argmin32(const float* __restrict__ x,
                                                     const ushort* __restrict__ ep,
                                                     const float* __restrict__ nrm,
                                                     int* __restrict__ idx,
                                                     int* __restrict__ wl1c,
                                                     int* __restrict__ wl1) {
    __shared__ float sb1[2][64];
    __shared__ float sb2[2][64];
    __shared__ int   sbi[2][64];

    const int tid = threadIdx.x;
    const int lane = tid & 63;
    const int w = tid >> 6;
    const int rtl = w & 1;            // rowtile in block
    const int nh = w >> 1;            // N-half
    const int rt = blockIdx.x * 2 + rtl;
    const int lrow = lane & 31;       // A-row / B-col inside tile
    const int lgrp = lane >> 5;       // k-group

    // A fragments: row = rt*32 + lrow, k(l,j) = lgrp*8 + j (same bijection as pack_e)
    const float* xr = x + (size_t)(rt * 32 + lrow) * DDIM + (lgrp << 3);
    short8 ah[8];
    #pragma unroll
    for (int c = 0; c < 8; ++c) {
        float4 u = *reinterpret_cast<const float4*>(xr + c * 16);
        float4 v = *reinterpret_cast<const float4*>(xr + c * 16 + 4);
        short8 a;
        a[0] = f2bf(u.x); a[1] = f2bf(u.y); a[2] = f2bf(u.z); a[3] = f2bf(u.w);
        a[4] = f2bf(v.x); a[5] = f2bf(v.y); a[6] = f2bf(v.z); a[7] = f2bf(v.w);
        ah[c] = a;
    }

    float b1[16], b2[16]; int bi[16];
    #pragma unroll
    for (int r = 0; r < 16; ++r) { b1[r] = 3.4e38f; b2[r] = 3.4e38f; bi[r] = 0; }

    const uint4* ep4 = reinterpret_cast<const uint4*>(ep);

    for (int t = 0; t < 16; ++t) {
        const int nt = nh * 16 + t;
        const float nv = nrm[nt * 32 + lrow];
        const int code = nt * 32 + lrow;

        f32x16 acc;
        #pragma unroll
        for (int r = 0; r < 16; ++r) acc[r] = 0.f;

        #pragma unroll
        for (int c = 0; c < 8; ++c) {
            union { uint4 q; short8 s; } cv;
            cv.q = ep4[(nt * 8 + c) * 64 + lane];
            acc = __builtin_amdgcn_mfma_f32_32x32x16_bf16(ah[c], cv.s, acc, 0, 0, 0);
        }

        #pragma unroll
        for (int r = 0; r < 16; ++r) {
            float s = fmaf(-2.f, acc[r], nv);
            bool lt = s < b1[r];
            float nb2 = lt ? b1[r] : fminf(b2[r], s);
            b1[r] = lt ? s : b1[r];
            bi[r] = lt ? code : bi[r];
            b2[r] = nb2;
        }
    }

    // reduce over the 32 columns (lanes sharing lgrp): butterfly, first-min tiebreak
    #pragma unroll
    for (int r = 0; r < 16; ++r) {
        #pragma unroll
        for (int m = 1; m < 32; m <<= 1) {
            float o1 = __shfl_xor(b1[r], m);
            float o2 = __shfl_xor(b2[r], m);
            int   oi = __shfl_xor(bi[r], m);
            bool take = (o1 < b1[r]) || (o1 == b1[r] && oi < bi[r]);
            float loser = take ? b1[r] : o1;
            b1[r] = take ? o1 : b1[r];
            bi[r] = take ? oi : bi[r];
            b2[r] = fminf(fminf(b2[r], o2), loser);
        }
    }

    if (lrow == 0) {
        #pragma unroll
        for (int r = 0; r < 16; ++r) {
            int rl = (r & 3) + 8 * (r >> 2) + 4 * lgrp;   // HW-verified C/D row map
            sb1[nh][rtl * 32 + rl] = b1[r];
            sb2[nh][rtl * 32 + rl] = b2[r];
            sbi[nh][rtl * 32 + rl] = bi[r];
        }
    }
    __syncthreads();
    if (nh == 0 && lrow == 0) {
        #pragma unroll
        for (int r = 0; r < 16; ++r) {
            int rl = (r & 3) + 8 * (r >> 2) + 4 * lgrp;
            int i = rtl * 32 + rl;
            float a1 = sb1[0][i], a2 = sb2[0][i]; int ai = sbi[0][i];
            float c1 = sb1[1][i], c2 = sb2[1][i]; int ci = sbi[1][i];
            bool take = (c1 < a1);                 // half0 has lower codes: keep on tie
            float loser = take ? a1 : c1;
            float f1 = take ? c1 : a1;
            int   fi = take ? ci : ai;
            float f2 = fminf(fminf(a2, c2), loser);
            int row = rt * 32 + rl;
            idx[row] = fi;
            if (f2 - f1 < MARGIN1) {
                int slot = atomicAdd(wl1c, 1);
                wl1[slot] = row;
            }
        }
    }
}

// ---------- phase 2/3: batched refine (T = float then double) ----------
template <typename T, bool FINAL>
__global__ __launch_bounds__(256) void k_refine(const float* __restrict__ x,
                                                const float* __restrict__ e,
                                                const double* __restrict__ nrm64,
                                                const int* __restrict__ wc_in,
                                                const int* __restrict__ wl_in,
                                                int* __restrict__ idx,
                                                int* __restrict__ wc_out,
                                                int* __restrict__ wl_out) {
    __shared__ float  xs[8][DDIM];
    __shared__ double r1[256], r2[256];
    __shared__ int    ri[256];
    const int tid = threadIdx.x;
    const int n = *wc_in;

    for (int g0 = blockIdx.x * 8; g0 < n; g0 += gridDim.x * 8) {
        const int nr = min(8, n - g0);
        for (int i = tid; i < 8 * DDIM; i += 256) {
            int j = i >> 7;
            xs[j][i & 127] = (j < nr) ? x[(size_t)wl_in[g0 + j] * DDIM + (i & 127)] : 0.f;
        }
        __syncthreads();

        T dots[4][8];
        #pragma unroll
        for (int kk = 0; kk < 4; ++kk)
            #pragma unroll
            for (int j = 0; j < 8; ++j) dots[kk][j] = (T)0;

        for (int d = 0; d < DDIM; ++d) {
            float xv[8];
            #pragma unroll
            for (int j = 0; j < 8; ++j) xv[j] = xs[j][d];
            #pragma unroll
            for (int kk = 0; kk < 4; ++kk) {
                T ev = (T)e[d * KCODES + tid + kk * 256];
                #pragma unroll
                for (int j = 0; j < 8; ++j)
                    dots[kk][j] += (T)xv[j] * ev;
            }
        }

        for (int j = 0; j < 8; ++j) {
            double bb1 = 1e300, bb2 = 1e300; int bbi = 0;
            #pragma unroll
            for (int kk = 0; kk < 4; ++kk) {
                int k = tid + kk * 256;                 // ascending per thread
                double sc = nrm64[k] - 2.0 * (double)dots[kk][j];
                if (sc < bb1) { bb2 = bb1; bb1 = sc; bbi = k; }
                else if (sc < bb2) bb2 = sc;
            }
            r1[tid] = bb1; r2[tid] = bb2; ri[tid] = bbi;
            __syncthreads();
            for (int off = 128; off > 0; off >>= 1) {
                if (tid < off) {
                    double o1 = r1[tid + off], o2 = r2[tid + off]; int oi = ri[tid + off];
                    bool take = (o1 < r1[tid]) || (o1 == r1[tid] && oi < ri[tid]);
                    double loser = take ? r1[tid] : o1;
                    if (take) { r1[tid] = o1; ri[tid] = oi; }
                    r2[tid] = fmin(fmin(r2[tid], o2), loser);
                }
                __syncthreads();
            }
            if (tid == 0 && j < nr) {
                int row = wl_in[g0 + j];
                idx[row] = ri[0];
                if (!FINAL && (r2[0] - r1[0] < MARGIN2)) {
                    int slot = atomicAdd(wc_out, 1);
                    wl_out[slot] = row;
                }
            }
            __syncthreads();
        }
    }
}

// ---------- gather + f32 STE ----------
__global__ void k_gather(const float* __restrict__ x, const float* __restrict__ et,
                         const int* __restrict__ idxp, float* __restrict__ out) {
    int gid = blockIdx.x * blockDim.x + threadIdx.x;   // NROWS*32
    int row = gid >> 5, d4 = gid & 31;
    float4 q = reinterpret_cast<const float4*>(et)[(size_t)idxp[row] * 32 + d4];
    float4 xv = reinterpret_cast<const float4*>(x)[gid];
    float4 o;
    o.x = xv.x + (q.x - xv.x);
    o.y = xv.y + (q.y - xv.y);
    o.z = xv.z + (q.z - xv.z);
    o.w = xv.w + (q.w - xv.w);
    reinterpret_cast<float4*>(out)[gid] = o;
}

extern "C" void kernel_launch(void* const* d_in, const int* in_sizes, int n_in,
                              void* d_out, int out_size, void* d_ws, size_t ws_size,
                              hipStream_t stream) {
    const float* x = (const float*)d_in[0];
    const float* e = (const float*)d_in[1];
    float* out = (float*)d_out;

    // ws layout (f32 slot units; every segment 16B-aligned)
    double* nrm64 = (double*)d_ws;                       // 1024 d  (2048 slots)
    float*  et    = (float*)d_ws + 2048;                 // 131072
    float*  nrm   = et + 131072;                         // 1024
    int*    idx   = (int*)(nrm + 1024);                  // 65536
    int*    wlc   = idx + NROWS;                         // 4 (wl1c, wl2c, pad)
    int*    wl1   = wlc + 4;                             // 65536
    int*    wl2   = wl1 + NROWS;                         // 65536
    ushort* ep    = (ushort*)(wl2 + NROWS);              // 131072 u16

    hipMemsetAsync(wlc, 0, 2 * sizeof(int), stream);

    k_transpose<<<(KCODES * DDIM) / 256, 256, 0, stream>>>(e, et);
    k_norms<<<KCODES / 256, 256, 0, stream>>>(e, nrm, nrm64);
    k_pack_e<<<16384 / 256, 256, 0, stream>>>(e, ep);
    k_argmin32<<<NROWS / 64, 256, 0, stream>>>(x, ep, nrm, idx, wlc, wl1);
    k_refine<float, false><<<512, 256, 0, stream>>>(x, e, nrm64, wlc, wl1, idx, wlc + 1, wl2);
    k_refine<double, true><<<128, 256, 0, stream>>>(x, e, nrm64, wlc + 1, wl2, idx, nullptr, nullptr);
    k_gather<<<(NROWS * 32) / 256, 256, 0, stream>>>(x, et, idx, out);
}

// Round 4
// 101.114 us; speedup vs baseline: 31.1431x; 2.4341x over previous
//
#include <hip/hip_runtime.h>

// VectorQuantizer: x (64,32,32,128) f32, embeddings (128,1024) f32.
// out = x + (q - x), q = e.T[argmin_k ||x_row - e_k||^2]   (same f32 ops as ref)
//
// Cascade:
//   phase 1: split-bf16 MFMA (32x32x16): dot = xh.eh + xh.el + xl.eh (3 MFMAs,
//            f32 acc). score = nrm32[k] - 2*dot. sigma ~ 1e-4; rows with
//            (2nd best - best) < MARGIN1 = 4e-3 (~40 sigma) -> worklist (~40 rows).
//   phase 2: f64 exact re-argmin of worklist rows (one row per block).
// A/B packed with the SAME k-bijection (dot invariant to consistent k-perm).
// C/D layout: col=lane&31, row=(reg&3)+8*(reg>>2)+4*(lane>>5)  [HW-verified].

#define NROWS 65536
#define DDIM 128
#define KCODES 1024
#define MARGIN1 0.004f

typedef __attribute__((ext_vector_type(8))) short short8;
typedef __attribute__((ext_vector_type(16))) float f32x16;

__device__ inline ushort f2bf(float f) {            // RNE f32 -> bf16 bits
    union { float f; unsigned u; } v; v.f = f;
    unsigned r = v.u + 0x7fffu + ((v.u >> 16) & 1u);
    return (ushort)(r >> 16);
}
__device__ inline float bf2f(ushort b) {
    union { unsigned u; float f; } v; v.u = ((unsigned)b) << 16;
    return v.f;
}

// ---------- prep ----------
__global__ void k_transpose(const float* __restrict__ e, float* __restrict__ et) {
    int gid = blockIdx.x * blockDim.x + threadIdx.x;   // 131072
    int d = gid >> 10, k = gid & 1023;
    et[k * DDIM + d] = e[gid];
}

__global__ void k_norms(const float* __restrict__ e, float* __restrict__ nrm,
                        double* __restrict__ nrm64) {
    int k = blockIdx.x * blockDim.x + threadIdx.x;     // 1024
    double s = 0.0;
    for (int d = 0; d < DDIM; ++d) {
        double v = (double)e[d * KCODES + k];
        s = fma(v, v, s);
    }
    nrm64[k] = s; nrm[k] = (float)s;
}

// epq slot = nt*1024 + h*512 + c*64 + lane  (uint4 = 8 bf16)
// holds e_{h}[k = c*16 + (lane>>5)*8 + j][code = nt*32 + (lane&31)]
__global__ void k_pack_e(const float* __restrict__ e, uint4* __restrict__ epq) {
    int t = blockIdx.x * blockDim.x + threadIdx.x;     // 32768
    int lane = t & 63, c = (t >> 6) & 7, h = (t >> 9) & 1, nt = t >> 10;
    int col = nt * 32 + (lane & 31);
    int kbase = c * 16 + ((lane >> 5) << 3);
    union { ushort u[8]; uint4 q; } pk;
    #pragma unroll
    for (int j = 0; j < 8; ++j) {
        float v = e[(kbase + j) * KCODES + col];
        ushort hb = f2bf(v);
        pk.u[j] = (h == 0) ? hb : f2bf(v - bf2f(hb));
    }
    epq[(size_t)nt * 1024 + h * 512 + c * 64 + lane] = pk.q;
}

// ---------- phase 1: split-bf16 MFMA argmin ----------
// grid 512 x 256. Block = 4 waves = 4 rowtiles; each wave scans all 32 e-tiles.
// e-tiles double-buffered in LDS (16 KB/tile: 512 hi + 512 lo uint4).
__global__ __launch_bounds__(256, 2) void k_argmin32(const float* __restrict__ x,
                                                     const uint4* __restrict__ epq,
                                                     const float* __restrict__ nrm,
                                                     int* __restrict__ idx,
                                                     int* __restrict__ wlc,
                                                     int* __restrict__ wl) {
    __shared__ uint4 sbuf[2][1024];                    // 32 KB

    const int tid = threadIdx.x;
    const int lane = tid & 63;
    const int w = tid >> 6;                            // rowtile in block
    const int rt = blockIdx.x * 4 + w;
    const int lrow = lane & 31;
    const int lgrp = lane >> 5;

    // A fragments (hi/lo): row = rt*32+lrow, k(c,j) = c*16 + lgrp*8 + j
    const float* xr = x + (size_t)(rt * 32 + lrow) * DDIM + (lgrp << 3);
    short8 ah[8], al[8];
    #pragma unroll
    for (int c = 0; c < 8; ++c) {
        float4 u = *reinterpret_cast<const float4*>(xr + c * 16);
        float4 v = *reinterpret_cast<const float4*>(xr + c * 16 + 4);
        float fv[8] = {u.x, u.y, u.z, u.w, v.x, v.y, v.z, v.w};
        short8 hi, lo;
        #pragma unroll
        for (int j = 0; j < 8; ++j) {
            ushort hb = f2bf(fv[j]);
            hi[j] = (short)hb;
            lo[j] = (short)f2bf(fv[j] - bf2f(hb));
        }
        ah[c] = hi; al[c] = lo;
    }

    float b1[16], b2[16]; int bi[16];
    #pragma unroll
    for (int r = 0; r < 16; ++r) { b1[r] = 3.4e38f; b2[r] = 3.4e38f; bi[r] = 0; }

    // prologue: stage tile 0
    uint4 st[4];
    #pragma unroll
    for (int i = 0; i < 4; ++i) st[i] = epq[i * 256 + tid];
    #pragma unroll
    for (int i = 0; i < 4; ++i) sbuf[0][i * 256 + tid] = st[i];

    int cur = 0;
    for (int t = 0; t < 32; ++t) {
        __syncthreads();
        if (t + 1 < 32) {
            #pragma unroll
            for (int i = 0; i < 4; ++i)
                st[i] = epq[(size_t)(t + 1) * 1024 + i * 256 + tid];
        }
        const float nv = nrm[t * 32 + lrow];
        const int code = t * 32 + lrow;

        f32x16 acc;
        #pragma unroll
        for (int r = 0; r < 16; ++r) acc[r] = 0.f;

        #pragma unroll
        for (int c = 0; c < 8; ++c) {
            union { uint4 q; short8 s; } bh, bl;
            bh.q = sbuf[cur][c * 64 + lane];
            bl.q = sbuf[cur][512 + c * 64 + lane];
            acc = __builtin_amdgcn_mfma_f32_32x32x16_bf16(ah[c], bh.s, acc, 0, 0, 0);
            acc = __builtin_amdgcn_mfma_f32_32x32x16_bf16(ah[c], bl.s, acc, 0, 0, 0);
            acc = __builtin_amdgcn_mfma_f32_32x32x16_bf16(al[c], bh.s, acc, 0, 0, 0);
        }
        if (t + 1 < 32) {
            #pragma unroll
            for (int i = 0; i < 4; ++i) sbuf[cur ^ 1][i * 256 + tid] = st[i];
        }

        #pragma unroll
        for (int r = 0; r < 16; ++r) {
            float s = fmaf(-2.f, acc[r], nv);
            bool lt = s < b1[r];
            b2[r] = lt ? b1[r] : fminf(b2[r], s);
            b1[r] = lt ? s : b1[r];
            bi[r] = lt ? code : bi[r];
        }
        cur ^= 1;
    }

    // butterfly over the 32 columns (each 32-lane half independently)
    #pragma unroll
    for (int r = 0; r < 16; ++r) {
        #pragma unroll
        for (int m = 1; m < 32; m <<= 1) {
            float o1 = __shfl_xor(b1[r], m);
            float o2 = __shfl_xor(b2[r], m);
            int   oi = __shfl_xor(bi[r], m);
            bool take = (o1 < b1[r]) || (o1 == b1[r] && oi < bi[r]);
            float loser = take ? b1[r] : o1;
            b1[r] = take ? o1 : b1[r];
            bi[r] = take ? oi : bi[r];
            b2[r] = fminf(fminf(b2[r], o2), loser);
        }
    }

    if (lrow == 0) {
        #pragma unroll
        for (int r = 0; r < 16; ++r) {
            int rl = (r & 3) + 8 * (r >> 2) + 4 * lgrp;   // HW-verified C/D row map
            int row = rt * 32 + rl;
            idx[row] = bi[r];
            if (b2[r] - b1[r] < MARGIN1) {
                int slot = atomicAdd(wlc, 1);
                wl[slot] = row;
            }
        }
    }
}

// ---------- phase 2: exact f64 re-argmin, one row per block ----------
__global__ __launch_bounds__(256) void k_fix(const float* __restrict__ x,
                                             const float* __restrict__ e,
                                             const double* __restrict__ nrm64,
                                             const int* __restrict__ wlc,
                                             const int* __restrict__ wl,
                                             int* __restrict__ idx) {
    __shared__ float  xs[DDIM];
    __shared__ double w1[4]; __shared__ double w2_[4]; __shared__ int wi[4];
    const int tid = threadIdx.x;
    const int lane = tid & 63;
    const int wv = tid >> 6;
    const int n = *wlc;

    for (int i = blockIdx.x; i < n; i += gridDim.x) {
        const int row = wl[i];
        if (tid < DDIM) xs[tid] = x[(size_t)row * DDIM + tid];
        __syncthreads();

        double dot[4] = {0.0, 0.0, 0.0, 0.0};
        for (int d0 = 0; d0 < DDIM; d0 += 8) {
            float ef[8][4];
            #pragma unroll
            for (int dd = 0; dd < 8; ++dd)
                #pragma unroll
                for (int kk = 0; kk < 4; ++kk)
                    ef[dd][kk] = e[(d0 + dd) * KCODES + tid + kk * 256];
            #pragma unroll
            for (int dd = 0; dd < 8; ++dd) {
                double xv = (double)xs[d0 + dd];
                #pragma unroll
                for (int kk = 0; kk < 4; ++kk)
                    dot[kk] = fma(xv, (double)ef[dd][kk], dot[kk]);
            }
        }

        double bb1 = 1e300, bb2 = 1e300; int bbi = 0;
        #pragma unroll
        for (int kk = 0; kk < 4; ++kk) {
            int k = tid + kk * 256;                  // ascending per thread
            double sc = nrm64[k] - 2.0 * dot[kk];
            if (sc < bb1) { bb2 = bb1; bb1 = sc; bbi = k; }
            else if (sc < bb2) bb2 = sc;
        }
        #pragma unroll
        for (int m = 1; m < 64; m <<= 1) {
            double o1 = __shfl_xor(bb1, m);
            int    oi = __shfl_xor(bbi, m);
            bool take = (o1 < bb1) || (o1 == bb1 && oi < bbi);
            bb1 = take ? o1 : bb1;
            bbi = take ? oi : bbi;
        }
        if (lane == 0) { w1[wv] = bb1; wi[wv] = bbi; }
        __syncthreads();
        if (tid == 0) {
            double f1 = w1[0]; int fi = wi[0];
            #pragma unroll
            for (int j = 1; j < 4; ++j) {
                bool take = (w1[j] < f1) || (w1[j] == f1 && wi[j] < fi);
                f1 = take ? w1[j] : f1;
                fi = take ? wi[j] : fi;
            }
            idx[row] = fi;
        }
        __syncthreads();     // xs reused next iteration
    }
}

// ---------- gather + f32 STE ----------
__global__ void k_gather(const float* __restrict__ x, const float* __restrict__ et,
                         const int* __restrict__ idxp, float* __restrict__ out) {
    int gid = blockIdx.x * blockDim.x + threadIdx.x;   // NROWS*32
    int row = gid >> 5, d4 = gid & 31;
    float4 q = reinterpret_cast<const float4*>(et)[(size_t)idxp[row] * 32 + d4];
    float4 xv = reinterpret_cast<const float4*>(x)[gid];
    float4 o;
    o.x = xv.x + (q.x - xv.x);
    o.y = xv.y + (q.y - xv.y);
    o.z = xv.z + (q.z - xv.z);
    o.w = xv.w + (q.w - xv.w);
    reinterpret_cast<float4*>(out)[gid] = o;
}

extern "C" void kernel_launch(void* const* d_in, const int* in_sizes, int n_in,
                              void* d_out, int out_size, void* d_ws, size_t ws_size,
                              hipStream_t stream) {
    const float* x = (const float*)d_in[0];
    const float* e = (const float*)d_in[1];
    float* out = (float*)d_out;

    // ws layout (f32 slot units; all segments 16B-aligned)
    double* nrm64 = (double*)d_ws;                       // 1024 d   (2048 slots)
    float*  et    = (float*)d_ws + 2048;                 // 131072
    float*  nrm   = et + 131072;                         // 1024
    int*    idx   = (int*)(nrm + 1024);                  // 65536
    int*    wlc   = idx + NROWS;                         // 4
    int*    wl    = wlc + 4;                             // 65536
    uint4*  epq   = (uint4*)(wl + NROWS);                // 32768 uint4 = 512 KB

    hipMemsetAsync(wlc, 0, sizeof(int), stream);

    k_transpose<<<(KCODES * DDIM) / 256, 256, 0, stream>>>(e, et);
    k_norms<<<KCODES / 256, 256, 0, stream>>>(e, nrm, nrm64);
    k_pack_e<<<32768 / 256, 256, 0, stream>>>(e, epq);
    k_argmin32<<<NROWS / 128, 256, 0, stream>>>(x, epq, nrm, idx, wlc, wl);
    k_fix<<<64, 256, 0, stream>>>(x, e, nrm64, wlc, wl, idx);
    k_gather<<<(NROWS * 32) / 256, 256, 0, stream>>>(x, et, idx, out);
}